// Round 1
// baseline (11.675 us; speedup 1.0000x reference)
//
#include <hip/hip_runtime.h>
#include <math.h>

// Problem constants (from setup_inputs): B=64, C=16, Lc=64, Ls=48, V=32000
#define NB 64
#define NC 16
#define LC 64
#define LS 48

// Kernel 1: one 64-lane wave per (b,c) pair. Computes
//   dot      = #{(i,j): src[b,i]==cand[b,c,j], tok!=pad}
//   ref_n2   = #{(i,i'): src equal pairs, tok!=pad}
//   cand_n2  = #{(j,j'): cand equal pairs, tok!=pad}
// score = 1 - dot / (sqrt(ref_n2)*sqrt(cand_n2))
__global__ void ngram_scores_kernel(const int* __restrict__ cand,
                                    const int* __restrict__ src,
                                    const int* __restrict__ pad_ptr,
                                    float* __restrict__ scores) {
    const int bc   = blockIdx.x;          // 0 .. NB*NC-1
    const int b    = bc / NC;
    const int lane = threadIdx.x;         // 0 .. 63
    const int pad  = pad_ptr[0];

    __shared__ int s_src[LS];
    __shared__ int s_cand[LC];
    if (lane < LS) s_src[lane] = src[b * LS + lane];
    s_cand[lane] = cand[bc * LC + lane];
    __syncthreads();

    int rn = 0;                           // ref norm^2 partial
    if (lane < LS) {
        const int t = s_src[lane];
        if (t != pad) {
            #pragma unroll
            for (int j = 0; j < LS; ++j) rn += (s_src[j] == t);
        }
    }

    int cn = 0, dt = 0;                   // cand norm^2, dot partials
    {
        const int t = s_cand[lane];
        if (t != pad) {
            #pragma unroll
            for (int j = 0; j < LC; ++j) cn += (s_cand[j] == t);
            // src[j]==t implies src[j]!=pad since t!=pad
            #pragma unroll
            for (int j = 0; j < LS; ++j) dt += (s_src[j] == t);
        }
    }

    // 64-lane butterfly reduce
    #pragma unroll
    for (int off = 32; off > 0; off >>= 1) {
        rn += __shfl_down(rn, off, 64);
        cn += __shfl_down(cn, off, 64);
        dt += __shfl_down(dt, off, 64);
    }

    if (lane == 0) {
        const float denom = sqrtf((float)rn) * sqrtf((float)cn);
        scores[bc] = 1.0f - (float)dt / denom;
    }
}

// Kernel 2: one 64-lane wave per b. Stable descending rank of the 16
// scores (ties -> lower index first, matching stable argsort(-scores)),
// then write:
//   out[0 .. NB*LC)                 : winning candidate tokens (float)
//   out[NB*LC .. NB*LC+NB)          : out_lengths (float)
//   out[NB*LC+NB .. +NB*NC)         : sorted_scores (float)
__global__ void ngram_finalize_kernel(const int* __restrict__ cand,
                                      const int* __restrict__ pad_ptr,
                                      const float* __restrict__ scores,
                                      float* __restrict__ out) {
    const int b    = blockIdx.x;
    const int lane = threadIdx.x;         // 0 .. 63
    const int pad  = pad_ptr[0];

    __shared__ float s_sc[NC];
    __shared__ int   s_best;
    if (lane < NC) s_sc[lane] = scores[b * NC + lane];
    __syncthreads();

    if (lane < NC) {
        const float s = s_sc[lane];
        int rank = 0;
        #pragma unroll
        for (int j = 0; j < NC; ++j) {
            const float t = s_sc[j];
            rank += (t > s) || (t == s && j < lane);
        }
        out[NB * LC + NB + b * NC + rank] = s;     // sorted_scores
        if (rank == 0) s_best = lane;
    }
    __syncthreads();

    const int best = s_best;
    const int tok  = cand[(b * NC + best) * LC + lane];
    out[b * LC + lane] = (float)tok;               // output tokens

    const unsigned long long m = __ballot(tok != pad);
    if (lane == 0) out[NB * LC + b] = (float)__popcll(m);  // out_lengths
}

extern "C" void kernel_launch(void* const* d_in, const int* in_sizes, int n_in,
                              void* d_out, int out_size, void* d_ws, size_t ws_size,
                              hipStream_t stream) {
    const int* cand = (const int*)d_in[0];   // [NB, NC, LC] int32
    const int* src  = (const int*)d_in[1];   // [NB, LS] int32
    // d_in[2] = vocab_size (unused: pairwise counting needs no histogram)
    const int* pad  = (const int*)d_in[3];   // pad_id

    float* scores = (float*)d_ws;            // NB*NC floats of scratch
    float* out    = (float*)d_out;           // 4096 + 64 + 1024 floats

    ngram_scores_kernel<<<NB * NC, 64, 0, stream>>>(cand, src, pad, scores);
    ngram_finalize_kernel<<<NB, 64, 0, stream>>>(cand, pad, scores, out);
}

// Round 2
// 10.512 us; speedup vs baseline: 1.1106x; 1.1106x over previous
//
#include <hip/hip_runtime.h>
#include <math.h>

// Problem constants (from setup_inputs): B=64, C=16, Lc=64, Ls=48, V=32000
#define NB 64
#define NC 16
#define LC 64
#define LS 48

// Fully fused: one block per batch b, 16 waves (one per candidate).
// Per block:
//   stage src[b] (48 ints) + cand[b] (16x64 ints) in LDS
//   wave w: dot/norm counts for candidate w -> score in LDS
//   rank 16 scores (stable desc), write sorted_scores
//   wave 0: write winning tokens + non-pad length
// Output layout (concatenated, all float32):
//   out[0 .. NB*LC)            winning candidate tokens
//   out[NB*LC .. NB*LC+NB)     out_lengths
//   out[NB*LC+NB .. +NB*NC)    sorted_scores
__global__ __launch_bounds__(NC * 64) void ngram_fused_kernel(
        const int* __restrict__ cand,
        const int* __restrict__ src,
        const int* __restrict__ pad_ptr,
        float* __restrict__ out) {
    const int b    = blockIdx.x;
    const int tid  = threadIdx.x;       // 0 .. 1023
    const int wave = tid >> 6;          // candidate index 0 .. 15
    const int lane = tid & 63;
    const int pad  = pad_ptr[0];

    __shared__ int   s_src[LS];
    __shared__ int   s_cand[NC][LC];
    __shared__ float s_sc[NC];
    __shared__ int   s_best;

    if (tid < LS) s_src[tid] = src[b * LS + tid];
    s_cand[wave][lane] = cand[(b * NC + wave) * LC + lane];
    __syncthreads();

    // ref norm^2 partial (same for all waves; redundant compute is free here)
    int rn = 0;
    if (lane < LS) {
        const int t = s_src[lane];
        if (t != pad) {
            #pragma unroll
            for (int j = 0; j < LS; ++j) rn += (s_src[j] == t);
        }
    }

    // cand norm^2 and dot partials for this wave's candidate
    int cn = 0, dt = 0;
    {
        const int t = s_cand[wave][lane];
        if (t != pad) {
            #pragma unroll
            for (int j = 0; j < LC; ++j) cn += (s_cand[wave][j] == t);
            // src[j]==t implies src[j]!=pad since t!=pad
            #pragma unroll
            for (int j = 0; j < LS; ++j) dt += (s_src[j] == t);
        }
    }

    // 64-lane reduce within the wave
    #pragma unroll
    for (int off = 32; off > 0; off >>= 1) {
        rn += __shfl_down(rn, off, 64);
        cn += __shfl_down(cn, off, 64);
        dt += __shfl_down(dt, off, 64);
    }

    if (lane == 0) {
        const float denom = sqrtf((float)rn) * sqrtf((float)cn);
        s_sc[wave] = 1.0f - (float)dt / denom;
    }
    __syncthreads();

    // stable descending rank of the 16 scores (tie -> lower index first),
    // matching jnp.argsort(-scores) stable semantics
    if (tid < NC) {
        const float s = s_sc[tid];
        int rank = 0;
        #pragma unroll
        for (int j = 0; j < NC; ++j) {
            const float t = s_sc[j];
            rank += (t > s) || (t == s && j < tid);
        }
        out[NB * LC + NB + b * NC + rank] = s;      // sorted_scores
        if (rank == 0) s_best = tid;
    }
    __syncthreads();

    if (wave == 0) {
        const int tok = s_cand[s_best][lane];
        out[b * LC + lane] = (float)tok;            // output tokens
        const unsigned long long m = __ballot(tok != pad);
        if (lane == 0) out[NB * LC + b] = (float)__popcll(m);  // out_lengths
    }
}

extern "C" void kernel_launch(void* const* d_in, const int* in_sizes, int n_in,
                              void* d_out, int out_size, void* d_ws, size_t ws_size,
                              hipStream_t stream) {
    const int* cand = (const int*)d_in[0];   // [NB, NC, LC] int32
    const int* src  = (const int*)d_in[1];   // [NB, LS] int32
    // d_in[2] = vocab_size (unused: pairwise counting needs no histogram)
    const int* pad  = (const int*)d_in[3];   // pad_id

    float* out = (float*)d_out;              // 4096 + 64 + 1024 floats

    ngram_fused_kernel<<<NB, NC * 64, 0, stream>>>(cand, src, pad, out);
}